// Round 1
// baseline (306.056 us; speedup 1.0000x reference)
//
#include <hip/hip_runtime.h>
#include <stdint.h>

typedef unsigned short u16;
typedef __attribute__((ext_vector_type(8))) short short8;
typedef __attribute__((ext_vector_type(4))) float floatx4;

#define DEV static __device__ __forceinline__

struct alignas(8) us4 { u16 x, y, z, w; };
struct alignas(16) f4 { float x, y, z, w; };

DEV u16 f2bf(float f) {
  uint32_t u = __float_as_uint(f);
  u += 0x7fffu + ((u >> 16) & 1u);
  return (u16)(u >> 16);
}
DEV float bf2f(u16 h) { return __uint_as_float(((uint32_t)h) << 16); }

DEV void load_lds16(const void* g, void* l) {
  __builtin_amdgcn_global_load_lds((const __attribute__((address_space(1))) void*)g,
                                   (__attribute__((address_space(3))) void*)l, 16, 0, 0);
}

// ---------------- elementwise fp32 -> bf16 ----------------
__global__ void cvt_f32_bf16(const float* __restrict__ in, u16* __restrict__ out, int n) {
  int i = (blockIdx.x * blockDim.x + threadIdx.x) * 4;
  if (i < n) {
    f4 v = *(const f4*)(in + i);
    us4 o; o.x = f2bf(v.x); o.y = f2bf(v.y); o.z = f2bf(v.z); o.w = f2bf(v.w);
    *(us4*)(out + i) = o;
  }
}

// ---------------- transpose + convert: W[K][N] fp32 -> WT[N][K] bf16 ----------------
__global__ void transpose_cvt(const float* __restrict__ in, u16* __restrict__ out, int K, int N) {
  __shared__ float tile[32][33];
  const int n0 = blockIdx.x * 32, k0 = blockIdx.y * 32;
  const int tx = threadIdx.x, ty = threadIdx.y;
  for (int i = ty; i < 32; i += 8)
    tile[i][tx] = in[(size_t)(k0 + i) * N + n0 + tx];
  __syncthreads();
  for (int i = ty; i < 32; i += 8)
    out[(size_t)(n0 + i) * K + k0 + tx] = f2bf(tile[tx][i]);
}

// ---------------- bf16 GEMM, C = A[M,K] * Bt[N,K]^T + bias ----------------
// EPI 0: scatter-write to qkv_pre [3][2][16][2048][64] bf16
// EPI 1: write float [M][N] (d_out)
template <int EPI>
__global__ __launch_bounds__(256) void gemm_bt(const u16* __restrict__ A,
                                               const u16* __restrict__ Bt,
                                               const float* __restrict__ bias,
                                               void* __restrict__ outp,
                                               int M, int N, int K) {
  __shared__ u16 lA[128 * 64];
  __shared__ u16 lB[128 * 64];
  const int t = threadIdx.x;
  const int w = t >> 6, lane = t & 63;
  const int quad = lane >> 4, l15 = lane & 15;
  const int wm = w >> 1, wn = w & 1;
  const int m0 = blockIdx.y * 128, n0 = blockIdx.x * 128;

  floatx4 acc[4][4] = {};

  const int srow = t >> 3;
  const int scol = (((t & 7) ^ (srow & 7)) << 3);  // XOR-swizzled source chunk
  const u16* gA = A + (size_t)(m0 + srow) * K + scol;
  const u16* gB = Bt + (size_t)(n0 + srow) * K + scol;
  u16* sA = lA + t * 8;
  u16* sB = lB + t * 8;
  const size_t rstep = (size_t)32 * K;

  for (int k0 = 0; k0 < K; k0 += 64) {
#pragma unroll
    for (int c = 0; c < 4; c++) {
      load_lds16(gA + c * rstep, sA + c * 2048);
      load_lds16(gB + c * rstep, sB + c * 2048);
    }
    gA += 64; gB += 64;
    __syncthreads();
#pragma unroll
    for (int kc = 0; kc < 2; kc++) {
      short8 af[4], bfr[4];
#pragma unroll
      for (int mt = 0; mt < 4; mt++)
        af[mt] = *(const short8*)&lA[(wm * 64 + mt * 16 + l15) * 64 + (((kc * 4 + quad) ^ (l15 & 7)) << 3)];
#pragma unroll
      for (int nt = 0; nt < 4; nt++)
        bfr[nt] = *(const short8*)&lB[(wn * 64 + nt * 16 + l15) * 64 + (((kc * 4 + quad) ^ (l15 & 7)) << 3)];
#pragma unroll
      for (int mt = 0; mt < 4; mt++)
#pragma unroll
        for (int nt = 0; nt < 4; nt++)
          acc[mt][nt] = __builtin_amdgcn_mfma_f32_16x16x32_bf16(af[mt], bfr[nt], acc[mt][nt], 0, 0, 0);
    }
    __syncthreads();
  }

  if (EPI == 0) {
    u16* outq = (u16*)outp;
#pragma unroll
    for (int nt = 0; nt < 4; nt++) {
      const int n = n0 + wn * 64 + nt * 16 + l15;
      const float bn = bias[n];
      const int tensor = n >> 10, e = n & 1023;
      const int h = e >> 6, d = e & 63;
      const size_t abase = (size_t)tensor * 4194304 + (size_t)h * 131072 + d;
#pragma unroll
      for (int mt = 0; mt < 4; mt++) {
        const int rb = m0 + wm * 64 + mt * 16 + quad * 4;
#pragma unroll
        for (int i = 0; i < 4; i++) {
          const int r = rb + i;
          const int b = r >> 11, s = r & 2047;
          outq[abase + (size_t)b * 2097152 + (size_t)s * 64] = f2bf(acc[mt][nt][i] + bn);
        }
      }
    }
  } else {
    float* outf = (float*)outp;
#pragma unroll
    for (int nt = 0; nt < 4; nt++) {
      const int n = n0 + wn * 64 + nt * 16 + l15;
      const float bn = bias[n];
#pragma unroll
      for (int mt = 0; mt < 4; mt++) {
        const int rb = m0 + wm * 64 + mt * 16 + quad * 4;
#pragma unroll
        for (int i = 0; i < 4; i++)
          outf[(size_t)(rb + i) * N + n] = acc[mt][nt][i] + bn;
      }
    }
  }
}

// ---------------- causal depthwise conv / head-mix ----------------
struct ConvW { const float* w[9]; const float* b[9]; };

__global__ __launch_bounds__(256) void conv_mix(const u16* __restrict__ qkv, ConvW cw,
                                                u16* __restrict__ qpost,
                                                u16* __restrict__ kpost,
                                                u16* __restrict__ vpostT) {
  __shared__ u16 xt[134 * 68];  // [s-halo 134][d 64 +4 pad]
  const int t = threadIdx.x;
  const int s0 = blockIdx.x * 128;
  const int h = blockIdx.y;
  const int tz = blockIdx.z;
  const int tensor = tz >> 1, b = tz & 1;
  const u16* src = qkv + (((size_t)tensor * 2 + b) * 16 + h) * 131072;

  for (int idx = t; idx < 134 * 16; idx += 256) {
    const int row = idx >> 4, c4 = (idx & 15) << 2;
    const int s = s0 - 6 + row;
    us4 v = {0, 0, 0, 0};
    if (s >= 0) v = *(const us4*)&src[(size_t)s * 64 + c4];
    *(us4*)&xt[row * 68 + c4] = v;
  }
  __syncthreads();

  const int group = h >> 2;
  const int ksz = group * 2 + 1;
  const float* wp = (group > 0) ? cw.w[tensor * 3 + group - 1] : nullptr;
  const float* bp = (group > 0) ? cw.b[tensor * 3 + group - 1] : nullptr;
  const float qscale = (tensor == 0) ? 0.125f : 1.0f;  // fold 1/sqrt(64) into Q (exact pow2)

  if (tensor < 2) {
    u16* outp = (tensor == 0) ? qpost : kpost;
    const size_t ob = (((size_t)b * 16 + h) * 2048 + s0) * 64;
    for (int i = 0; i < 32; i++) {
      const int lin = t + i * 256;
      const int sl = lin >> 6, d = lin & 63;
      float val;
      if (group == 0) {
        val = bf2f(xt[(sl + 6) * 68 + d]);
      } else {
        val = bp[d];
        for (int jj = 0; jj < ksz; jj++)
          val += wp[d * ksz + jj] * bf2f(xt[(sl + 6 - (ksz - 1) + jj) * 68 + d]);
      }
      outp[ob + (size_t)sl * 64 + d] = f2bf(val * qscale);
    }
  } else {
    const size_t ob = ((size_t)b * 16 + h) * 64;
    for (int i = 0; i < 32; i++) {
      const int lin = t + i * 256;
      const int d = lin >> 7, sl = lin & 127;
      float val;
      if (group == 0) {
        val = bf2f(xt[(sl + 6) * 68 + d]);
      } else {
        val = bp[d];
        for (int jj = 0; jj < ksz; jj++)
          val += wp[d * ksz + jj] * bf2f(xt[(sl + 6 - (ksz - 1) + jj) * 68 + d]);
      }
      vpostT[(ob + d) * 2048 + s0 + sl] = f2bf(val);  // transposed [B,H,D,S]
    }
  }
}

// ---------------- causal flash attention (S^T formulation) ----------------
// Q,K: [B,H,S,64] bf16 (Q pre-scaled by 1/8). V: [B,H,64,S] bf16. Out: [B,S,1024] bf16.
__global__ __launch_bounds__(256) void attn_fwd(const u16* __restrict__ Q,
                                                const u16* __restrict__ Kp,
                                                const u16* __restrict__ Vt,
                                                u16* __restrict__ Out) {
  __shared__ u16 lK[128 * 64];       // [kv][d]
  __shared__ u16 lV[64 * 128];       // [d][kv]
  __shared__ u16 lP[4][32 * 128];    // per wave: [q_local][kv]
  const int t = threadIdx.x;
  const int w = t >> 6, lane = t & 63;
  const int quad = lane >> 4, l15 = lane & 15;
  const int xb = blockIdx.x;
  const int qi = (xb & 1) ? (xb >> 1) : (15 - (xb >> 1));  // interleave heavy/light blocks
  const int bh = blockIdx.y;
  const int b = bh >> 4, h = bh & 15;
  const size_t qkbase = (size_t)bh * 131072;
  const int qblk = qi * 128 + w * 32;

  // Q fragments (B-operand): lane holds Q[q = l15 + 16*qt][d = kc*32 + quad*8 + j]
  short8 qf[2][2];
#pragma unroll
  for (int qt = 0; qt < 2; qt++)
#pragma unroll
    for (int kc = 0; kc < 2; kc++)
      qf[qt][kc] = *(const short8*)&Q[qkbase + (size_t)(qblk + qt * 16 + l15) * 64 + kc * 32 + quad * 8];

  float mst[2] = {-3.0e38f, -3.0e38f};
  float lst[2] = {0.0f, 0.0f};
  floatx4 accO[4][2] = {};

  const int krow = t >> 3;
  const int kcol = (((t & 7) ^ (krow & 7)) << 3);
  const u16* gK = Kp + qkbase + (size_t)krow * 64 + kcol;
  const int vrow = t >> 4;
  const int vcol = (((t & 15) ^ vrow) << 3);
  const u16* gV = Vt + qkbase + (size_t)vrow * 2048 + vcol;
  u16* sK = lK + t * 8;
  u16* sV = lV + t * 8;
  u16* myP = lP[w];

  for (int j = 0; j <= qi; j++) {
    const int j0 = j * 128;
#pragma unroll
    for (int c = 0; c < 4; c++) {
      load_lds16(gK + (size_t)(j0 + c * 32) * 64, sK + c * 2048);
      load_lds16(gV + j0 + c * 16 * 2048, sV + c * 2048);
    }
    __syncthreads();

    // S^T[kv][q] = K * Q^T
    floatx4 accS[8][2] = {};
#pragma unroll
    for (int kvt = 0; kvt < 8; kvt++) {
#pragma unroll
      for (int kc = 0; kc < 2; kc++) {
        const short8 a = *(const short8*)&lK[(kvt * 16 + l15) * 64 + (((kc * 4 + quad) ^ (l15 & 7)) << 3)];
#pragma unroll
        for (int qt = 0; qt < 2; qt++)
          accS[kvt][qt] = __builtin_amdgcn_mfma_f32_16x16x32_bf16(a, qf[qt][kc], accS[kvt][qt], 0, 0, 0);
      }
    }

    if (j == qi) {  // causal mask on diagonal tile
#pragma unroll
      for (int qt = 0; qt < 2; qt++) {
        const int q = qblk + qt * 16 + l15;
#pragma unroll
        for (int kvt = 0; kvt < 8; kvt++)
#pragma unroll
          for (int r = 0; r < 4; r++) {
            const int kv = j0 + kvt * 16 + quad * 4 + r;
            if (kv > q) accS[kvt][qt][r] = -3.0e38f;
          }
      }
    }

    float alpha[2];
#pragma unroll
    for (int qt = 0; qt < 2; qt++) {
      float tm = -3.0e38f;
#pragma unroll
      for (int kvt = 0; kvt < 8; kvt++)
#pragma unroll
        for (int r = 0; r < 4; r++)
          tm = fmaxf(tm, accS[kvt][qt][r]);
      tm = fmaxf(tm, __shfl_xor(tm, 16));
      tm = fmaxf(tm, __shfl_xor(tm, 32));
      const float mnew = fmaxf(mst[qt], tm);
      alpha[qt] = __expf(mst[qt] - mnew);
      mst[qt] = mnew;
      float ts = 0.0f;
      const int prow = (qt * 16 + l15) * 128;
#pragma unroll
      for (int kvt = 0; kvt < 8; kvt++) {
        const float p0 = __expf(accS[kvt][qt][0] - mnew);
        const float p1 = __expf(accS[kvt][qt][1] - mnew);
        const float p2 = __expf(accS[kvt][qt][2] - mnew);
        const float p3 = __expf(accS[kvt][qt][3] - mnew);
        ts += (p0 + p1) + (p2 + p3);
        us4 pk; pk.x = f2bf(p0); pk.y = f2bf(p1); pk.z = f2bf(p2); pk.w = f2bf(p3);
        const int slot = (kvt * 2 + (quad >> 1)) ^ (l15 & 7);  // 16B-chunk XOR swizzle
        *(us4*)&myP[prow + slot * 8 + (quad & 1) * 4] = pk;
      }
      ts += __shfl_xor(ts, 16);
      ts += __shfl_xor(ts, 32);
      lst[qt] = lst[qt] * alpha[qt] + ts;
    }

#pragma unroll
    for (int dt = 0; dt < 4; dt++)
#pragma unroll
      for (int qt = 0; qt < 2; qt++)
#pragma unroll
        for (int r = 0; r < 4; r++)
          accO[dt][qt][r] *= alpha[qt];

    asm volatile("s_waitcnt lgkmcnt(0)" ::: "memory");  // P writes visible to own wave

    // O^T[d][q] += V^T * P^T
#pragma unroll
    for (int kvc = 0; kvc < 4; kvc++) {
      short8 pf[2];
#pragma unroll
      for (int qt = 0; qt < 2; qt++)
        pf[qt] = *(const short8*)&myP[(qt * 16 + l15) * 128 + (((kvc * 4 + quad) ^ (l15 & 7)) << 3)];
#pragma unroll
      for (int dt = 0; dt < 4; dt++) {
        const short8 vf = *(const short8*)&lV[(dt * 16 + l15) * 128 + (((kvc * 4 + quad) ^ l15) << 3)];
#pragma unroll
        for (int qt = 0; qt < 2; qt++)
          accO[dt][qt] = __builtin_amdgcn_mfma_f32_16x16x32_bf16(vf, pf[qt], accO[dt][qt], 0, 0, 0);
      }
    }
    __syncthreads();
  }

  // epilogue: O[q][d] = O^T / l, write bf16 [B,S,E]
#pragma unroll
  for (int qt = 0; qt < 2; qt++) {
    const float inv = 1.0f / lst[qt];
    const int q = qblk + qt * 16 + l15;
#pragma unroll
    for (int dt = 0; dt < 4; dt++) {
      us4 o;
      o.x = f2bf(accO[dt][qt][0] * inv);
      o.y = f2bf(accO[dt][qt][1] * inv);
      o.z = f2bf(accO[dt][qt][2] * inv);
      o.w = f2bf(accO[dt][qt][3] * inv);
      *(us4*)&Out[((size_t)b * 2048 + q) * 1024 + h * 64 + dt * 16 + quad * 4] = o;
    }
  }
}

// ---------------- launcher ----------------
extern "C" void kernel_launch(void* const* d_in, const int* in_sizes, int n_in,
                              void* d_out, int out_size, void* d_ws, size_t ws_size,
                              hipStream_t stream) {
  (void)in_sizes; (void)n_in; (void)out_size; (void)ws_size;
  const float* hidden = (const float*)d_in[0];
  const float* attn_w = (const float*)d_in[1];
  const float* attn_b = (const float*)d_in[2];
  const float* proj_w = (const float*)d_in[3];
  const float* proj_b = (const float*)d_in[4];
  ConvW cw;
  for (int i = 0; i < 9; i++) {
    cw.w[i] = (const float*)d_in[5 + 2 * i];
    cw.b[i] = (const float*)d_in[6 + 2 * i];
  }

  uint8_t* ws = (uint8_t*)d_ws;
  u16* h_bf   = (u16*)(ws + 0);          //  8,388,608 B  hidden bf16 [4096][1024]
  u16* wqkvT  = (u16*)(ws + 8388608);    //  6,291,456 B  c_attn_w^T bf16 [3072][1024]
  u16* wprojT = (u16*)(ws + 14680064);   //  2,097,152 B  c_proj_w^T bf16 [1024][1024]
  u16* qkvpre = (u16*)(ws + 16777216);   // 25,165,824 B  [3][2][16][2048][64]
  u16* qpost  = (u16*)(ws + 41943040);   //  8,388,608 B  [2][16][2048][64]
  u16* kpost  = (u16*)(ws + 50331648);   //  8,388,608 B
  u16* vpostT = (u16*)(ws + 58720256);   //  8,388,608 B  [2][16][64][2048]
  u16* attno  = (u16*)(ws + 67108864);   //  8,388,608 B  [2][2048][1024]

  cvt_f32_bf16<<<4096, 256, 0, stream>>>(hidden, h_bf, 4194304);
  transpose_cvt<<<dim3(96, 32), dim3(32, 8), 0, stream>>>(attn_w, wqkvT, 1024, 3072);
  transpose_cvt<<<dim3(32, 32), dim3(32, 8), 0, stream>>>(proj_w, wprojT, 1024, 1024);
  gemm_bt<0><<<dim3(24, 32), 256, 0, stream>>>(h_bf, wqkvT, attn_b, (void*)qkvpre, 4096, 3072, 1024);
  conv_mix<<<dim3(16, 16, 6), 256, 0, stream>>>(qkvpre, cw, qpost, kpost, vpostT);
  attn_fwd<<<dim3(16, 32), 256, 0, stream>>>(qpost, kpost, vpostT, attno);
  gemm_bt<1><<<dim3(8, 32), 256, 0, stream>>>(attno, wprojT, proj_b, d_out, 4096, 1024, 1024);
}